// Round 18
// baseline (104.303 us; speedup 1.0000x reference)
//
#include <hip/hip_runtime.h>
#include <math.h>
#include <stdint.h>

#define KCODES 512
#define DIM 64
#define ROWB 72               // padded LDS/ws row stride in bytes (64 + 8 pad)
#define NROWS (64 * 4096)     // B*S = 262144
#define BLOCK 512             // 8 waves
#define ROWS_PER_WAVE 16      // one 16-row mf tile per wave
#define BM ((BLOCK / 64) * ROWS_PER_WAVE)   // 128 rows per block
#define NBLK (NROWS / BM)                   // 2048 blocks; 4/CU resident, 8 gens
#define LOSS_SCALE 1048576.0  // 2^20 fixed-point for deterministic atomic sum

typedef float f32x4 __attribute__((ext_vector_type(4)));
typedef long long i64t;

typedef __attribute__((address_space(3))) uint32_t* lds_ptr_t;
typedef const __attribute__((address_space(1))) uint32_t* glb_ptr_t;

// ---------------------------------------------------------------------------
// Kernel A (prep, runs once per launch): per code k
//   en512[k] = 512 * (1 + ||e_k||^2)      (exact fp32; acc-init, pre-scaled)
//   ebf8[k*72 + j*8 .. +7] = fp8_e4m3(-1024 * e_k[j*8..])   (padded rows;
//   pad bytes never read; padding lives in the ws image so linear
//   global_load_lds staging reproduces it in LDS).
// Also zeroes the loss accumulator + completion counter (graph replays the
// whole sequence, so state is re-initialized every launch).
// 72 B rows -> ds_read_b64 bank = (18*l15 + 2*c) % 32, injective over the
// 16-lane quarter -> conflict-free. [verified R13]
// ---------------------------------------------------------------------------
__global__ void vq_prep_kernel(const float* __restrict__ emb,
                               float* __restrict__ en512,
                               uint8_t* __restrict__ ebf8,
                               unsigned long long* __restrict__ lacc,
                               unsigned int* __restrict__ counter) {
    if (blockIdx.x == 0 && threadIdx.x == 0) {
        *lacc = 0ULL;
        *counter = 0u;
    }
    int k = blockIdx.x * blockDim.x + threadIdx.x;
    if (k >= KCODES) return;
    const float4* e4 = reinterpret_cast<const float4*>(emb + k * DIM);
    float s0 = 0.f, s1 = 0.f, s2 = 0.f, s3 = 0.f;
#pragma unroll
    for (int j = 0; j < 8; ++j) {
        float4 v0 = e4[j * 2];
        float4 v1 = e4[j * 2 + 1];
        s0 = fmaf(v0.x, v0.x, s0); s1 = fmaf(v0.y, v0.y, s1);
        s2 = fmaf(v0.z, v0.z, s2); s3 = fmaf(v0.w, v0.w, s3);
        s0 = fmaf(v1.x, v1.x, s0); s1 = fmaf(v1.y, v1.y, s1);
        s2 = fmaf(v1.z, v1.z, s2); s3 = fmaf(v1.w, v1.w, s3);
        uint32_t lo = 0, hi = 0;
        lo = __builtin_amdgcn_cvt_pk_fp8_f32(-1024.f * v0.x, -1024.f * v0.y, lo, false);
        lo = __builtin_amdgcn_cvt_pk_fp8_f32(-1024.f * v0.z, -1024.f * v0.w, lo, true);
        hi = __builtin_amdgcn_cvt_pk_fp8_f32(-1024.f * v1.x, -1024.f * v1.y, hi, false);
        hi = __builtin_amdgcn_cvt_pk_fp8_f32(-1024.f * v1.z, -1024.f * v1.w, hi, true);
        uint2 p; p.x = lo; p.y = hi;
        *reinterpret_cast<uint2*>(&ebf8[k * ROWB + (j << 3)]) = p;
    }
    en512[k] = 512.f * (1.0f + (s0 + s1) + (s2 + s3));
}

// ---------------------------------------------------------------------------
// Kernel B (R13/R17 core + fused loss finalize): fp8 MFMA scoring +
// packed-key argmin + per-wave gather + deterministic fixed-point loss.
//   512*(score+1) = en512[k] + fp8(x) . fp8(-1024 e_k)   (acc-init = en512)
//   positive -> as_uint monotone; key = (bits & ~511) | k ; umin; tie -> min k.
//   loss row-sum = key/512 - 1 + ||x||^2 (exact xsq from fp32 regs).
// Loss: per-block partial -> llrintf(x * 2^20) -> u64 atomicAdd (integer,
// order-independent => bitwise deterministic). Last-finishing block (device
// counter) finalizes loss[0]. No third kernel.
// 39 KB LDS -> 4 blocks/CU x 8 waves = 100% occupancy cap; NBLK=2048 gives
// 8 generations of block turnover.
// ---------------------------------------------------------------------------
__launch_bounds__(BLOCK, 8)
__global__ void vq_mfma_kernel(const float* __restrict__ lat,
                               const float* __restrict__ emb,
                               const float* __restrict__ en512,
                               const uint8_t* __restrict__ ebf8,
                               float* __restrict__ outq,
                               float* __restrict__ loss,
                               unsigned long long* __restrict__ lacc,
                               unsigned int* __restrict__ counter) {
    __shared__ __align__(16) uint8_t e_lds[KCODES * ROWB];  // 36864 B, padded
    __shared__ float en_lds[KCODES];                        // 2 KB
    __shared__ float wsum_lds[BLOCK / 64];

    const int t = threadIdx.x;
    const int lane = t & 63, wid = t >> 6;
    const int l15 = lane & 15, lq = lane >> 4;

    // XCD-aware bijective swizzle (2048 % 8 == 0)
    const uint32_t bid = (blockIdx.x & 7) * (NBLK / 8) + (blockIdx.x >> 3);
    const uint32_t waverow = bid * BM + (uint32_t)wid * ROWS_PER_WAVE;

    // ---- A loads FIRST (longest latency): 16 rows/wave, raw fp32.
    float4 araw[2][2];   // [ks][half]
#pragma unroll
    for (int ks = 0; ks < 2; ++ks) {
        const float* xp = lat + (waverow + l15) * DIM + ks * 32 + lq * 8;
        araw[ks][0] = reinterpret_cast<const float4*>(xp)[0];
        araw[ks][1] = reinterpret_cast<const float4*>(xp)[1];
    }

    // ---- stage E image (incl. pads): 2304 x 16B chunks, linear.
#pragma unroll
    for (int i = 0; i < 4; ++i) {
        int c = t + i * BLOCK;
        __builtin_amdgcn_global_load_lds(
            (glb_ptr_t)(const void*)(ebf8 + c * 16),
            (lds_ptr_t)(void*)(&e_lds[c * 16]), 16, 0, 0);
    }
    if (t < 256) {   // waves 0-3, wave-uniform branch
        int c = 2048 + t;
        __builtin_amdgcn_global_load_lds(
            (glb_ptr_t)(const void*)(ebf8 + c * 16),
            (lds_ptr_t)(void*)(&e_lds[c * 16]), 16, 0, 0);
    }
    en_lds[t] = en512[t];   // BLOCK == KCODES
    __syncthreads();        // vmcnt drain: A + E + en ready (only barrier)

    // ---- cvt A -> fp8 frags (k = 8*lq + b per ks-half); exact ||x||^2
    float xsq = 0.f, lsum = 0.f;
    i64t afrag[2];
#pragma unroll
    for (int ks = 0; ks < 2; ++ks) {
        float4 v0 = araw[ks][0], v1 = araw[ks][1];
        xsq = fmaf(v0.x, v0.x, xsq); xsq = fmaf(v0.y, v0.y, xsq);
        xsq = fmaf(v0.z, v0.z, xsq); xsq = fmaf(v0.w, v0.w, xsq);
        xsq = fmaf(v1.x, v1.x, xsq); xsq = fmaf(v1.y, v1.y, xsq);
        xsq = fmaf(v1.z, v1.z, xsq); xsq = fmaf(v1.w, v1.w, xsq);
        uint32_t lo = 0, hi = 0;
        lo = __builtin_amdgcn_cvt_pk_fp8_f32(v0.x, v0.y, lo, false);
        lo = __builtin_amdgcn_cvt_pk_fp8_f32(v0.z, v0.w, lo, true);
        hi = __builtin_amdgcn_cvt_pk_fp8_f32(v1.x, v1.y, hi, false);
        hi = __builtin_amdgcn_cvt_pk_fp8_f32(v1.z, v1.w, hi, true);
        afrag[ks] = (i64t)(((uint64_t)hi << 32) | (uint64_t)lo);
    }

    uint32_t best[4];
#pragma unroll
    for (int r = 0; r < 4; ++r) best[r] = 0xFFFFFFFFu;

    // ---- score loop: 32 groups of 16 codes; conflict-free b64 LDS reads.
#pragma unroll 4
    for (int nf = 0; nf < 32; ++nf) {
        const int n = nf * 16 + l15;
        const uint8_t* p = &e_lds[n * ROWB + (lq << 3)];
        i64t b0 = *reinterpret_cast<const i64t*>(p);        // elems 8lq..
        i64t b1 = *reinterpret_cast<const i64t*>(p + 32);   // elems 32+8lq..
        float en = en_lds[n];
        f32x4 acc = {en, en, en, en};
        acc = __builtin_amdgcn_mfma_f32_16x16x32_fp8_fp8(afrag[0], b0, acc, 0, 0, 0);
        acc = __builtin_amdgcn_mfma_f32_16x16x32_fp8_fp8(afrag[1], b1, acc, 0, 0, 0);
        const uint32_t nn = (uint32_t)n;
#pragma unroll
        for (int r = 0; r < 4; ++r) {
            uint32_t k = (__float_as_uint(acc[r]) & 0xFFFFFE00u) | nn;
            best[r] = min(best[r], k);
        }
    }

    // ---- cross-lane umin butterfly: ALL 16 col-lanes end with row minima
#pragma unroll
    for (int off = 1; off < 16; off <<= 1) {
#pragma unroll
        for (int r = 0; r < 4; ++r) {
            uint32_t o = (uint32_t)__shfl_xor((int)best[r], off, 64);
            best[r] = min(best[r], o);
        }
    }

    // ---- loss from keys: row-sum (q-x)^2 = key/512 - 1 + ||x||^2
    if (l15 == 0) {
#pragma unroll
        for (int r = 0; r < 4; ++r)
            lsum = fmaf(__uint_as_float(best[r] & 0xFFFFFE00u),
                        (1.f / 512.f), lsum - 1.0f);
    }

    // ---- per-wave gather: lane (lq,l15) writes chunk l15 of row
    // waverow + lq*4 + r; emb (128 KB fp32) is L2-resident.
    const float4* emb4 = reinterpret_cast<const float4*>(emb);
    float4* out4 = reinterpret_cast<float4*>(outq);
#pragma unroll
    for (int r = 0; r < 4; ++r) {
        const uint32_t k = best[r] & 511u;
        const uint32_t grow = waverow + lq * 4 + r;
        float4 e4 = emb4[k * 16 + l15];
        out4[grow * 16 + l15] = e4;
    }

    lsum += xsq;

    // ---- deterministic block reduce -> fixed-point atomic -> last block
    // finalizes loss (integer adds are order-independent).
#pragma unroll
    for (int off = 32; off > 0; off >>= 1)
        lsum += __shfl_down(lsum, off, 64);
    if (lane == 0) wsum_lds[wid] = lsum;
    __syncthreads();
    if (t == 0) {
        float s = 0.f;
#pragma unroll
        for (int w = 0; w < BLOCK / 64; ++w) s += wsum_lds[w];
        long long fx = llrintf(s * (float)LOSS_SCALE);
        atomicAdd(lacc, (unsigned long long)fx);
        __threadfence();
        unsigned int done = atomicAdd(counter, 1u);
        if (done == NBLK - 1) {
            unsigned long long tot = atomicAdd(lacc, 0ULL);  // device-scope read
            double total = (double)(long long)tot / LOSS_SCALE;
            loss[0] = (float)(1.25 * total / ((double)NROWS * DIM));
        }
    }
}

// ---------------------------------------------------------------------------
extern "C" void kernel_launch(void* const* d_in, const int* in_sizes, int n_in,
                              void* d_out, int out_size, void* d_ws, size_t ws_size,
                              hipStream_t stream) {
    const float* lat = (const float*)d_in[0];   // [B,S,D] fp32
    const float* emb = (const float*)d_in[1];   // [K,D]   fp32
    float* outq = (float*)d_out;                              // output 0
    float* loss = (float*)d_out + (size_t)NROWS * DIM;        // output 1

    // ws layout (bytes): [0,2048)        en512 f32[512]
    //                    [2048, 38912)   ebf8 fp8[512*72] (padded rows, -1024x)
    //                    [38912, 38920)  lacc u64 (fixed-point loss accum)
    //                    [38920, 38924)  counter u32 (block completion)
    float* en512 = (float*)d_ws;
    uint8_t* ebf8 = (uint8_t*)d_ws + 2048;
    unsigned long long* lacc = (unsigned long long*)((char*)d_ws + 38912);
    unsigned int* counter = (unsigned int*)((char*)d_ws + 38920);

    vq_prep_kernel<<<2, 256, 0, stream>>>(emb, en512, ebf8, lacc, counter);
    vq_mfma_kernel<<<NBLK, BLOCK, 0, stream>>>(lat, emb, en512, ebf8, outq,
                                               loss, lacc, counter);
}

// Round 19
// 39.168 us; speedup vs baseline: 2.6630x; 2.6630x over previous
//
#include <hip/hip_runtime.h>
#include <math.h>
#include <stdint.h>

#define KCODES 512
#define DIM 64
#define ROWB 72               // padded LDS/ws row stride in bytes (64 + 8 pad)
#define NROWS (64 * 4096)     // B*S = 262144
#define BLOCK 512             // 8 waves
#define ROWS_PER_WAVE 16      // one 16-row mf tile per wave
#define BM ((BLOCK / 64) * ROWS_PER_WAVE)   // 128 rows per block
#define NBLK (NROWS / BM)                   // 2048 blocks; 4/CU resident, 8 gens

typedef float f32x4 __attribute__((ext_vector_type(4)));
typedef long long i64t;

typedef __attribute__((address_space(3))) uint32_t* lds_ptr_t;
typedef const __attribute__((address_space(1))) uint32_t* glb_ptr_t;

// ---------------------------------------------------------------------------
// Kernel A (prep, runs once): per code k
//   en512[k] = 512 * (1 + ||e_k||^2)      (exact fp32; acc-init, pre-scaled)
//   ebf8[k*72 + j*8 .. +7] = fp8_e4m3(-1024 * e_k[j*8..])   (padded rows;
//   pad bytes never read; padding lives in the ws image so linear
//   global_load_lds staging reproduces it in LDS).
// 72 B rows -> ds_read_b64 bank = (18*l15 + 2*c) % 32, injective over the
// 16-lane quarter -> conflict-free, no XOR swizzle anywhere. [verified R13]
// ---------------------------------------------------------------------------
__global__ void vq_prep_kernel(const float* __restrict__ emb,
                               float* __restrict__ en512,
                               uint8_t* __restrict__ ebf8) {
    int k = blockIdx.x * blockDim.x + threadIdx.x;
    if (k >= KCODES) return;
    const float4* e4 = reinterpret_cast<const float4*>(emb + k * DIM);
    float s0 = 0.f, s1 = 0.f, s2 = 0.f, s3 = 0.f;
#pragma unroll
    for (int j = 0; j < 8; ++j) {
        float4 v0 = e4[j * 2];
        float4 v1 = e4[j * 2 + 1];
        s0 = fmaf(v0.x, v0.x, s0); s1 = fmaf(v0.y, v0.y, s1);
        s2 = fmaf(v0.z, v0.z, s2); s3 = fmaf(v0.w, v0.w, s3);
        s0 = fmaf(v1.x, v1.x, s0); s1 = fmaf(v1.y, v1.y, s1);
        s2 = fmaf(v1.z, v1.z, s2); s3 = fmaf(v1.w, v1.w, s3);
        uint32_t lo = 0, hi = 0;
        lo = __builtin_amdgcn_cvt_pk_fp8_f32(-1024.f * v0.x, -1024.f * v0.y, lo, false);
        lo = __builtin_amdgcn_cvt_pk_fp8_f32(-1024.f * v0.z, -1024.f * v0.w, lo, true);
        hi = __builtin_amdgcn_cvt_pk_fp8_f32(-1024.f * v1.x, -1024.f * v1.y, hi, false);
        hi = __builtin_amdgcn_cvt_pk_fp8_f32(-1024.f * v1.z, -1024.f * v1.w, hi, true);
        uint2 p; p.x = lo; p.y = hi;
        *reinterpret_cast<uint2*>(&ebf8[k * ROWB + (j << 3)]) = p;
    }
    en512[k] = 512.f * (1.0f + (s0 + s1) + (s2 + s3));
}

// ---------------------------------------------------------------------------
// Kernel B (R13, best verified 39.5 us — final): fp8 MFMA scoring +
// packed-key argmin + per-wave gather + loss partial.
//   512*(score+1) = en512[k] + fp8(x) . fp8(-1024 e_k)   (acc-init = en512)
//   positive -> as_uint monotone; key = (bits & ~511) | k ; umin; tie -> min k.
//   loss row-sum = key/512 - 1 + ||x||^2 (exact xsq from fp32 regs).
// 39 KB LDS -> 4 blocks/CU x 8 waves = 100% occupancy cap; NBLK=2048 gives
// 8 generations of block turnover. Loss finalized by a separate tiny kernel
// (R18 showed per-block device-scope fences cost ~90us on 8-XCD CDNA4).
// ---------------------------------------------------------------------------
__launch_bounds__(BLOCK, 8)
__global__ void vq_mfma_kernel(const float* __restrict__ lat,
                               const float* __restrict__ emb,
                               const float* __restrict__ en512,
                               const uint8_t* __restrict__ ebf8,
                               float* __restrict__ outq,
                               float* __restrict__ partials) {
    __shared__ __align__(16) uint8_t e_lds[KCODES * ROWB];  // 36864 B, padded
    __shared__ float en_lds[KCODES];                        // 2 KB
    __shared__ float wsum_lds[BLOCK / 64];

    const int t = threadIdx.x;
    const int lane = t & 63, wid = t >> 6;
    const int l15 = lane & 15, lq = lane >> 4;

    // XCD-aware bijective swizzle (2048 % 8 == 0)
    const uint32_t bid = (blockIdx.x & 7) * (NBLK / 8) + (blockIdx.x >> 3);
    const uint32_t waverow = bid * BM + (uint32_t)wid * ROWS_PER_WAVE;

    // ---- stage E image (incl. pads): 2304 x 16B chunks, linear.
#pragma unroll
    for (int i = 0; i < 4; ++i) {
        int c = t + i * BLOCK;
        __builtin_amdgcn_global_load_lds(
            (glb_ptr_t)(const void*)(ebf8 + c * 16),
            (lds_ptr_t)(void*)(&e_lds[c * 16]), 16, 0, 0);
    }
    if (t < 256) {   // waves 0-3, wave-uniform branch
        int c = 2048 + t;
        __builtin_amdgcn_global_load_lds(
            (glb_ptr_t)(const void*)(ebf8 + c * 16),
            (lds_ptr_t)(void*)(&e_lds[c * 16]), 16, 0, 0);
    }

    // ---- A loads: 16 rows/wave, raw fp32 (4 x dwordx4 per lane).
    float4 araw[2][2];   // [ks][half]
#pragma unroll
    for (int ks = 0; ks < 2; ++ks) {
        const float* xp = lat + (waverow + l15) * DIM + ks * 32 + lq * 8;
        araw[ks][0] = reinterpret_cast<const float4*>(xp)[0];
        araw[ks][1] = reinterpret_cast<const float4*>(xp)[1];
    }
    en_lds[t] = en512[t];   // BLOCK == KCODES
    __syncthreads();        // vmcnt drain: E + en + A ready (only barrier)

    // ---- cvt A -> fp8 frags (k = 8*lq + b per ks-half); exact ||x||^2
    float xsq = 0.f, lsum = 0.f;
    i64t afrag[2];
#pragma unroll
    for (int ks = 0; ks < 2; ++ks) {
        float4 v0 = araw[ks][0], v1 = araw[ks][1];
        xsq = fmaf(v0.x, v0.x, xsq); xsq = fmaf(v0.y, v0.y, xsq);
        xsq = fmaf(v0.z, v0.z, xsq); xsq = fmaf(v0.w, v0.w, xsq);
        xsq = fmaf(v1.x, v1.x, xsq); xsq = fmaf(v1.y, v1.y, xsq);
        xsq = fmaf(v1.z, v1.z, xsq); xsq = fmaf(v1.w, v1.w, xsq);
        uint32_t lo = 0, hi = 0;
        lo = __builtin_amdgcn_cvt_pk_fp8_f32(v0.x, v0.y, lo, false);
        lo = __builtin_amdgcn_cvt_pk_fp8_f32(v0.z, v0.w, lo, true);
        hi = __builtin_amdgcn_cvt_pk_fp8_f32(v1.x, v1.y, hi, false);
        hi = __builtin_amdgcn_cvt_pk_fp8_f32(v1.z, v1.w, hi, true);
        afrag[ks] = (i64t)(((uint64_t)hi << 32) | (uint64_t)lo);
    }

    uint32_t best[4];
#pragma unroll
    for (int r = 0; r < 4; ++r) best[r] = 0xFFFFFFFFu;

    // ---- score loop: 32 groups of 16 codes; conflict-free b64 LDS reads.
#pragma unroll 4
    for (int nf = 0; nf < 32; ++nf) {
        const int n = nf * 16 + l15;
        const uint8_t* p = &e_lds[n * ROWB + (lq << 3)];
        i64t b0 = *reinterpret_cast<const i64t*>(p);        // elems 8lq..
        i64t b1 = *reinterpret_cast<const i64t*>(p + 32);   // elems 32+8lq..
        float en = en_lds[n];
        f32x4 acc = {en, en, en, en};
        acc = __builtin_amdgcn_mfma_f32_16x16x32_fp8_fp8(afrag[0], b0, acc, 0, 0, 0);
        acc = __builtin_amdgcn_mfma_f32_16x16x32_fp8_fp8(afrag[1], b1, acc, 0, 0, 0);
        const uint32_t nn = (uint32_t)n;
#pragma unroll
        for (int r = 0; r < 4; ++r) {
            uint32_t k = (__float_as_uint(acc[r]) & 0xFFFFFE00u) | nn;
            best[r] = min(best[r], k);
        }
    }

    // ---- cross-lane umin butterfly: ALL 16 col-lanes end with row minima
#pragma unroll
    for (int off = 1; off < 16; off <<= 1) {
#pragma unroll
        for (int r = 0; r < 4; ++r) {
            uint32_t o = (uint32_t)__shfl_xor((int)best[r], off, 64);
            best[r] = min(best[r], o);
        }
    }

    // ---- loss from keys: row-sum (q-x)^2 = key/512 - 1 + ||x||^2
    if (l15 == 0) {
#pragma unroll
        for (int r = 0; r < 4; ++r)
            lsum = fmaf(__uint_as_float(best[r] & 0xFFFFFE00u),
                        (1.f / 512.f), lsum - 1.0f);
    }

    // ---- per-wave gather: lane (lq,l15) writes chunk l15 of row
    // waverow + lq*4 + r; emb (128 KB fp32) is L2-resident.
    const float4* emb4 = reinterpret_cast<const float4*>(emb);
    float4* out4 = reinterpret_cast<float4*>(outq);
#pragma unroll
    for (int r = 0; r < 4; ++r) {
        const uint32_t k = best[r] & 511u;
        const uint32_t grow = waverow + lq * 4 + r;
        float4 e4 = emb4[k * 16 + l15];
        out4[grow * 16 + l15] = e4;
    }

    lsum += xsq;

    // ---- deterministic block reduce
#pragma unroll
    for (int off = 32; off > 0; off >>= 1)
        lsum += __shfl_down(lsum, off, 64);
    if (lane == 0) wsum_lds[wid] = lsum;
    __syncthreads();
    if (t == 0) {
        float s = 0.f;
#pragma unroll
        for (int w = 0; w < BLOCK / 64; ++w) s += wsum_lds[w];
        partials[blockIdx.x] = s;
    }
}

// ---------------------------------------------------------------------------
// Kernel C: reduce partials -> vq_loss = 1.25 * mean((q-x)^2)
// ---------------------------------------------------------------------------
__global__ void vq_loss_kernel(const float* __restrict__ partials,
                               float* __restrict__ loss) {
    float s = 0.f;
    for (int i = threadIdx.x; i < NBLK; i += 256) s += partials[i];
#pragma unroll
    for (int off = 32; off > 0; off >>= 1)
        s += __shfl_down(s, off, 64);
    __shared__ float wsum[4];
    const int lane = threadIdx.x & 63;
    const int wid = threadIdx.x >> 6;
    if (lane == 0) wsum[wid] = s;
    __syncthreads();
    if (threadIdx.x == 0) {
        float tsum = 0.f;
#pragma unroll
        for (int w = 0; w < 4; ++w) tsum += wsum[w];
        loss[0] = 1.25f * (tsum / (float)((size_t)NROWS * DIM));
    }
}

// ---------------------------------------------------------------------------
extern "C" void kernel_launch(void* const* d_in, const int* in_sizes, int n_in,
                              void* d_out, int out_size, void* d_ws, size_t ws_size,
                              hipStream_t stream) {
    const float* lat = (const float*)d_in[0];   // [B,S,D] fp32
    const float* emb = (const float*)d_in[1];   // [K,D]   fp32
    float* outq = (float*)d_out;                              // output 0
    float* loss = (float*)d_out + (size_t)NROWS * DIM;        // output 1

    // ws layout (bytes): [0,2048)        en512 f32[512]
    //                    [2048, 38912)   ebf8 fp8[512*72] (padded rows, -1024x)
    //                    [38912, 47104)  partials f32[2048]
    float* en512 = (float*)d_ws;
    uint8_t* ebf8 = (uint8_t*)d_ws + 2048;
    float* partials = (float*)((char*)d_ws + 38912);

    vq_prep_kernel<<<2, 256, 0, stream>>>(emb, en512, ebf8);
    vq_mfma_kernel<<<NBLK, BLOCK, 0, stream>>>(lat, emb, en512, ebf8, outq, partials);
    vq_loss_kernel<<<1, 256, 0, stream>>>(partials, loss);
}